// Round 1
// baseline (572.503 us; speedup 1.0000x reference)
//
#include <hip/hip_runtime.h>
#include <hip/hip_bf16.h>
#include <cstdint>

// Causal self-attention: x[4,2048,1024] @ Wqkv[1024,3072] -> QKV -> 16-head
// causal attention (HD=64) -> @ Wout[1024,1024] -> out fp32.
// Baseline: bf16 MFMA GEMMs (128x128 tile, 4 waves) + flash attention
// (64-row q-tiles, online softmax in fp32, LDS S/P staging per wave).

typedef __attribute__((ext_vector_type(8))) short bf16x8;
typedef __attribute__((ext_vector_type(4))) float f32x4;

#define MFMA_BF16(a, b, c) __builtin_amdgcn_mfma_f32_16x16x32_bf16((a), (b), (c), 0, 0, 0)

__device__ __forceinline__ ushort f2bf(float f) {
  union { float f; uint32_t u; } x;
  x.f = f;
  uint32_t u = x.u;
  return (ushort)((u + 0x7FFFu + ((u >> 16) & 1u)) >> 16);
}

// ---------------------------------------------------------------- convert x
__global__ __launch_bounds__(256) void convert_f32_bf16(
    const float* __restrict__ in, ushort* __restrict__ out, int n4) {
  int i = blockIdx.x * 256 + threadIdx.x;
  if (i < n4) {
    float4 v = ((const float4*)in)[i];
    ushort4 o;
    o.x = f2bf(v.x); o.y = f2bf(v.y); o.z = f2bf(v.z); o.w = f2bf(v.w);
    ((ushort4*)out)[i] = o;
  }
}

// ------------------------------------------------- W [K][N] f32 -> Wt [N][K] bf16
__global__ __launch_bounds__(256) void transpose_w(
    const float* __restrict__ W, ushort* __restrict__ Wt, int K, int N) {
  __shared__ float tile[32][33];
  const int n0 = blockIdx.x * 32, k0 = blockIdx.y * 32;
  const int tx = threadIdx.x & 31, ty = threadIdx.x >> 5;  // ty 0..7
#pragma unroll
  for (int i = 0; i < 4; ++i)
    tile[ty + i * 8][tx] = W[(size_t)(k0 + ty + i * 8) * N + n0 + tx];
  __syncthreads();
#pragma unroll
  for (int i = 0; i < 4; ++i)
    Wt[(size_t)(n0 + ty + i * 8) * K + k0 + tx] = f2bf(tile[tx][ty + i * 8]);
}

// ---------------------------------------------------------------- GEMM bf16
// A [M][K] bf16 row-major, Bt [N][K] bf16 row-major (B transposed).
// MODE 0: epilogue splits QKV -> q,k [BH][T][64] bf16, v transposed [BH][64][T].
// MODE 1: epilogue stores fp32 C [M][N].
template <int MODE>
__global__ __launch_bounds__(256) void gemm_bf16_kernel(
    const ushort* __restrict__ A, const ushort* __restrict__ Bt,
    float* __restrict__ C,
    ushort* __restrict__ qb, ushort* __restrict__ kb, ushort* __restrict__ vb,
    int M, int N, int K) {
  __shared__ ushort As[128][40];  // pad 40: 80B row stride, 16B aligned
  __shared__ ushort Bs[128][40];
  const int tid = threadIdx.x;
  const int lane = tid & 63;
  const int w = tid >> 6;
  const int wr = w >> 1, wc = w & 1;
  const int l15 = lane & 15, lhi = lane >> 4;
  const int row0 = blockIdx.x * 128, col0 = blockIdx.y * 128;
  const int ar = tid >> 2;
  const int ac = (tid & 3) << 3;

  f32x4 acc[4][4] = {};

  for (int k0 = 0; k0 < K; k0 += 32) {
    *(bf16x8*)&As[ar][ac]      = *(const bf16x8*)(A  + (size_t)(row0 + ar) * K + k0 + ac);
    *(bf16x8*)&As[ar + 64][ac] = *(const bf16x8*)(A  + (size_t)(row0 + ar + 64) * K + k0 + ac);
    *(bf16x8*)&Bs[ar][ac]      = *(const bf16x8*)(Bt + (size_t)(col0 + ar) * K + k0 + ac);
    *(bf16x8*)&Bs[ar + 64][ac] = *(const bf16x8*)(Bt + (size_t)(col0 + ar + 64) * K + k0 + ac);
    __syncthreads();
    bf16x8 af[4], bfr[4];
#pragma unroll
    for (int m = 0; m < 4; ++m)
      af[m] = *(const bf16x8*)&As[wr * 64 + m * 16 + l15][lhi * 8];
#pragma unroll
    for (int n = 0; n < 4; ++n)
      bfr[n] = *(const bf16x8*)&Bs[wc * 64 + n * 16 + l15][lhi * 8];
#pragma unroll
    for (int m = 0; m < 4; ++m)
#pragma unroll
      for (int n = 0; n < 4; ++n)
        acc[m][n] = MFMA_BF16(af[m], bfr[n], acc[m][n]);
    __syncthreads();
  }

  if (MODE == 1) {
#pragma unroll
    for (int m = 0; m < 4; ++m) {
      const int r0 = row0 + wr * 64 + m * 16 + lhi * 4;
#pragma unroll
      for (int n = 0; n < 4; ++n) {
        const int c = col0 + wc * 64 + n * 16 + l15;
#pragma unroll
        for (int j = 0; j < 4; ++j)
          C[(size_t)(r0 + j) * N + c] = acc[m][n][j];
      }
    }
  } else {
    // QKV split epilogue. c in [0,3072): seg = c/1024 (q/k/v), h = (c%1024)/64, d = c%64
#pragma unroll
    for (int m = 0; m < 4; ++m) {
      const int r0 = row0 + wr * 64 + m * 16 + lhi * 4;  // global token row (4 consecutive)
      const int b_ = r0 >> 11;
      const int t0 = r0 & 2047;
#pragma unroll
      for (int n = 0; n < 4; ++n) {
        const int c = col0 + wc * 64 + n * 16 + l15;
        const int seg = c >> 10;
        const int cc = c & 1023;
        const int h = cc >> 6, d = cc & 63;
        const size_t bhi = (size_t)(b_ * 16 + h);
        if (seg == 0) {
#pragma unroll
          for (int j = 0; j < 4; ++j)
            qb[(bhi * 2048 + t0 + j) * 64 + d] = f2bf(acc[m][n][j]);
        } else if (seg == 1) {
#pragma unroll
          for (int j = 0; j < 4; ++j)
            kb[(bhi * 2048 + t0 + j) * 64 + d] = f2bf(acc[m][n][j]);
        } else {
          ushort4 pk;
          pk.x = f2bf(acc[m][n][0]);
          pk.y = f2bf(acc[m][n][1]);
          pk.z = f2bf(acc[m][n][2]);
          pk.w = f2bf(acc[m][n][3]);
          *(ushort4*)(vb + (bhi * 64 + d) * 2048 + t0) = pk;  // V^T [BH][64][T]
        }
      }
    }
  }
}

// ------------------------------------------------------------- attention
// Q,K: [BH][2048][64] bf16.  Vt: [BH][64][2048] bf16.  Ab out: [B][T][H*64] bf16.
// Block: (qt, bh). 4 waves, wave w owns q rows [qt*64 + w*16, +16).
// Per 64-key tile: S = scale*Q K^T (MFMA) -> LDS, mask, online softmax (fp32),
// P bf16 -> LDS, O += P V (MFMA, Vt gives contiguous B-fragments).
__global__ __launch_bounds__(256) void attn_kernel(
    const ushort* __restrict__ Qb, const ushort* __restrict__ Kb,
    const ushort* __restrict__ Vt, ushort* __restrict__ Ab) {
  const int qt = blockIdx.x;   // 0..31
  const int bh = blockIdx.y;   // 0..63
  const int tid = threadIdx.x;
  const int lane = tid & 63;
  const int w = tid >> 6;
  const int l15 = lane & 15, lhi = lane >> 4;
  const int qloc = qt * 64 + w * 16;

  __shared__ float S[4][16][68];   // pad 68 floats: breaks 16-way bank conflict
  __shared__ ushort P[4][16][72];  // pad 72 ushorts (144B, 16B aligned rows)
  __shared__ float Mrow[4][16], Lrow[4][16], Alph[4][16];

  const size_t qkbase = (size_t)bh * (2048 * 64);
  const size_t vtb = (size_t)bh * (64 * 2048);

  bf16x8 qf[2];
#pragma unroll
  for (int kk = 0; kk < 2; ++kk)
    qf[kk] = *(const bf16x8*)(Qb + qkbase + (size_t)(qloc + l15) * 64 + kk * 32 + lhi * 8);

  if (lane < 16) { Mrow[w][lane] = -INFINITY; Lrow[w][lane] = 0.f; }
  asm volatile("s_waitcnt lgkmcnt(0)" ::: "memory");

  f32x4 o[4] = {};
  const float scale = 0.125f;  // 1/sqrt(64)

  for (int kbt = 0; kbt <= qt; ++kbt) {
    const int key0 = kbt * 64;
    // ---- S = Q K^T (rows=q, cols=key), scaled + causal mask -> LDS
#pragma unroll
    for (int kt = 0; kt < 4; ++kt) {
      f32x4 s = {};
      bf16x8 kf0 = *(const bf16x8*)(Kb + qkbase + (size_t)(key0 + kt * 16 + l15) * 64 + lhi * 8);
      bf16x8 kf1 = *(const bf16x8*)(Kb + qkbase + (size_t)(key0 + kt * 16 + l15) * 64 + 32 + lhi * 8);
      s = MFMA_BF16(qf[0], kf0, s);
      s = MFMA_BF16(qf[1], kf1, s);
#pragma unroll
      for (int j = 0; j < 4; ++j) {
        const int qrow = qloc + lhi * 4 + j;
        const int key = key0 + kt * 16 + l15;
        float v = s[j] * scale;
        if (key > qrow) v = -INFINITY;
        S[w][lhi * 4 + j][kt * 16 + l15] = v;
      }
    }
    asm volatile("s_waitcnt lgkmcnt(0)" ::: "memory");

    // ---- online softmax: lane handles row l15, cols lhi + 4*jj
    float mloc = -INFINITY;
    float vals[16];
#pragma unroll
    for (int jj = 0; jj < 16; ++jj) {
      vals[jj] = S[w][l15][lhi + 4 * jj];
      mloc = fmaxf(mloc, vals[jj]);
    }
    mloc = fmaxf(mloc, __shfl_xor(mloc, 16));
    mloc = fmaxf(mloc, __shfl_xor(mloc, 32));
    const float mold = Mrow[w][l15];
    const float mnew = fmaxf(mold, mloc);
    const float alpha = __expf(mold - mnew);  // first tile: exp(-inf)=0
    float lloc = 0.f;
#pragma unroll
    for (int jj = 0; jj < 16; ++jj) {
      const float p = __expf(vals[jj] - mnew);
      lloc += p;
      P[w][l15][lhi + 4 * jj] = f2bf(p);
    }
    lloc += __shfl_xor(lloc, 16);
    lloc += __shfl_xor(lloc, 32);
    if (lhi == 0) {
      Mrow[w][l15] = mnew;
      Lrow[w][l15] = Lrow[w][l15] * alpha + lloc;
      Alph[w][l15] = alpha;
    }
    asm volatile("s_waitcnt lgkmcnt(0)" ::: "memory");

    // ---- rescale O by alpha (row = lhi*4+j)
#pragma unroll
    for (int j = 0; j < 4; ++j) {
      const float a_ = Alph[w][lhi * 4 + j];
#pragma unroll
      for (int n = 0; n < 4; ++n) o[n][j] *= a_;
    }
    // ---- O += P V  (A-frag: P rows contiguous; B-frag: Vt rows contiguous)
#pragma unroll
    for (int n = 0; n < 4; ++n) {
#pragma unroll
      for (int ks = 0; ks < 2; ++ks) {
        bf16x8 pf = *(const bf16x8*)&P[w][l15][ks * 32 + lhi * 8];
        bf16x8 vf = *(const bf16x8*)(Vt + vtb + (size_t)(n * 16 + l15) * 2048 + key0 + ks * 32 + lhi * 8);
        o[n] = MFMA_BF16(pf, vf, o[n]);
      }
    }
  }

  asm volatile("s_waitcnt lgkmcnt(0)" ::: "memory");
  const int b_ = bh >> 4, h_ = bh & 15;
#pragma unroll
  for (int j = 0; j < 4; ++j) {
    const int t = qloc + lhi * 4 + j;
    const float inv = 1.0f / Lrow[w][lhi * 4 + j];
    const size_t ro = ((size_t)b_ * 2048 + t) * 1024 + h_ * 64;
#pragma unroll
    for (int n = 0; n < 4; ++n)
      Ab[ro + n * 16 + l15] = f2bf(o[n][j] * inv);
  }
}

// ---------------------------------------------------------------- launch
extern "C" void kernel_launch(void* const* d_in, const int* in_sizes, int n_in,
                              void* d_out, int out_size, void* d_ws, size_t ws_size,
                              hipStream_t stream) {
  const float* x = (const float*)d_in[0];
  const float* Wqkv = (const float*)d_in[1];
  const float* Wout = (const float*)d_in[2];
  float* out = (float*)d_out;

  // workspace layout (bf16 elements), total ~88 MB
  ushort* xb    = (ushort*)d_ws;                     // [8192][1024]
  ushort* wqkvT = xb + (size_t)8192 * 1024;          // [3072][1024]
  ushort* woutT = wqkvT + (size_t)3072 * 1024;       // [1024][1024]
  ushort* qb    = woutT + (size_t)1024 * 1024;       // [64][2048][64]
  ushort* kbuf  = qb + (size_t)64 * 2048 * 64;       // [64][2048][64]
  ushort* vbuf  = kbuf + (size_t)64 * 2048 * 64;     // [64][64][2048] (V^T)
  ushort* ab    = vbuf + (size_t)64 * 2048 * 64;     // [8192][1024]

  convert_f32_bf16<<<8192, 256, 0, stream>>>(x, xb, 8192 * 1024 / 4);
  transpose_w<<<dim3(96, 32), 256, 0, stream>>>(Wqkv, wqkvT, 1024, 3072);
  transpose_w<<<dim3(32, 32), 256, 0, stream>>>(Wout, woutT, 1024, 1024);
  gemm_bf16_kernel<0><<<dim3(64, 24), 256, 0, stream>>>(
      xb, wqkvT, nullptr, qb, kbuf, vbuf, 8192, 3072, 1024);
  attn_kernel<<<dim3(32, 64), 256, 0, stream>>>(qb, kbuf, vbuf, ab);
  gemm_bf16_kernel<1><<<dim3(64, 8), 256, 0, stream>>>(
      ab, woutT, out, nullptr, nullptr, nullptr, 8192, 1024, 1024);
}

// Round 2
// 355.642 us; speedup vs baseline: 1.6098x; 1.6098x over previous
//
#include <hip/hip_runtime.h>
#include <hip/hip_bf16.h>
#include <cstdint>

// Causal self-attention: x[4,2048,1024] @ Wqkv[1024,3072] -> QKV -> 16-head
// causal attention (HD=64) -> @ Wout[1024,1024] -> out fp32.
// R2: attention rewritten with swapped QK^T (mfma(K,Q)) so softmax is fully
// in-register (no S LDS round-trip, no M/L LDS state); P via one LDS trip
// packed with v_cvt_pk_bf16_f32; longest-first block order.

typedef __attribute__((ext_vector_type(8))) short bf16x8;
typedef __attribute__((ext_vector_type(4))) float f32x4;

#define MFMA_BF16(a, b, c) __builtin_amdgcn_mfma_f32_16x16x32_bf16((a), (b), (c), 0, 0, 0)

__device__ __forceinline__ ushort f2bf(float f) {
  union { float f; uint32_t u; } x;
  x.f = f;
  uint32_t u = x.u;
  return (ushort)((u + 0x7FFFu + ((u >> 16) & 1u)) >> 16);
}

__device__ __forceinline__ uint32_t cvt_pk_bf16(float lo, float hi) {
  uint32_t r;
  asm("v_cvt_pk_bf16_f32 %0, %1, %2" : "=v"(r) : "v"(lo), "v"(hi));
  return r;
}

// ---------------------------------------------------------------- convert x
__global__ __launch_bounds__(256) void convert_f32_bf16(
    const float* __restrict__ in, ushort* __restrict__ out, int n4) {
  int i = blockIdx.x * 256 + threadIdx.x;
  if (i < n4) {
    float4 v = ((const float4*)in)[i];
    ushort4 o;
    o.x = f2bf(v.x); o.y = f2bf(v.y); o.z = f2bf(v.z); o.w = f2bf(v.w);
    ((ushort4*)out)[i] = o;
  }
}

// ------------------------------------------------- W [K][N] f32 -> Wt [N][K] bf16
__global__ __launch_bounds__(256) void transpose_w(
    const float* __restrict__ W, ushort* __restrict__ Wt, int K, int N) {
  __shared__ float tile[32][33];
  const int n0 = blockIdx.x * 32, k0 = blockIdx.y * 32;
  const int tx = threadIdx.x & 31, ty = threadIdx.x >> 5;  // ty 0..7
#pragma unroll
  for (int i = 0; i < 4; ++i)
    tile[ty + i * 8][tx] = W[(size_t)(k0 + ty + i * 8) * N + n0 + tx];
  __syncthreads();
#pragma unroll
  for (int i = 0; i < 4; ++i)
    Wt[(size_t)(n0 + ty + i * 8) * K + k0 + tx] = f2bf(tile[tx][ty + i * 8]);
}

// ---------------------------------------------------------------- GEMM bf16
// A [M][K] bf16 row-major, Bt [N][K] bf16 row-major (B transposed).
// MODE 0: epilogue splits QKV -> q,k [BH][T][64] bf16, v transposed [BH][64][T].
// MODE 1: epilogue stores fp32 C [M][N].
template <int MODE>
__global__ __launch_bounds__(256) void gemm_bf16_kernel(
    const ushort* __restrict__ A, const ushort* __restrict__ Bt,
    float* __restrict__ C,
    ushort* __restrict__ qb, ushort* __restrict__ kb, ushort* __restrict__ vb,
    int M, int N, int K) {
  __shared__ ushort As[128][40];  // pad 40: 80B row stride, 16B aligned
  __shared__ ushort Bs[128][40];
  const int tid = threadIdx.x;
  const int lane = tid & 63;
  const int w = tid >> 6;
  const int wr = w >> 1, wc = w & 1;
  const int l15 = lane & 15, lhi = lane >> 4;
  const int row0 = blockIdx.x * 128, col0 = blockIdx.y * 128;
  const int ar = tid >> 2;
  const int ac = (tid & 3) << 3;

  f32x4 acc[4][4] = {};

  for (int k0 = 0; k0 < K; k0 += 32) {
    *(bf16x8*)&As[ar][ac]      = *(const bf16x8*)(A  + (size_t)(row0 + ar) * K + k0 + ac);
    *(bf16x8*)&As[ar + 64][ac] = *(const bf16x8*)(A  + (size_t)(row0 + ar + 64) * K + k0 + ac);
    *(bf16x8*)&Bs[ar][ac]      = *(const bf16x8*)(Bt + (size_t)(col0 + ar) * K + k0 + ac);
    *(bf16x8*)&Bs[ar + 64][ac] = *(const bf16x8*)(Bt + (size_t)(col0 + ar + 64) * K + k0 + ac);
    __syncthreads();
    bf16x8 af[4], bfr[4];
#pragma unroll
    for (int m = 0; m < 4; ++m)
      af[m] = *(const bf16x8*)&As[wr * 64 + m * 16 + l15][lhi * 8];
#pragma unroll
    for (int n = 0; n < 4; ++n)
      bfr[n] = *(const bf16x8*)&Bs[wc * 64 + n * 16 + l15][lhi * 8];
#pragma unroll
    for (int m = 0; m < 4; ++m)
#pragma unroll
      for (int n = 0; n < 4; ++n)
        acc[m][n] = MFMA_BF16(af[m], bfr[n], acc[m][n]);
    __syncthreads();
  }

  if (MODE == 1) {
#pragma unroll
    for (int m = 0; m < 4; ++m) {
      const int r0 = row0 + wr * 64 + m * 16 + lhi * 4;
#pragma unroll
      for (int n = 0; n < 4; ++n) {
        const int c = col0 + wc * 64 + n * 16 + l15;
#pragma unroll
        for (int j = 0; j < 4; ++j)
          C[(size_t)(r0 + j) * N + c] = acc[m][n][j];
      }
    }
  } else {
    // QKV split epilogue. c in [0,3072): seg = c/1024 (q/k/v), h = (c%1024)/64, d = c%64
#pragma unroll
    for (int m = 0; m < 4; ++m) {
      const int r0 = row0 + wr * 64 + m * 16 + lhi * 4;  // global token row (4 consecutive)
      const int b_ = r0 >> 11;
      const int t0 = r0 & 2047;
#pragma unroll
      for (int n = 0; n < 4; ++n) {
        const int c = col0 + wc * 64 + n * 16 + l15;
        const int seg = c >> 10;
        const int cc = c & 1023;
        const int h = cc >> 6, d = cc & 63;
        const size_t bhi = (size_t)(b_ * 16 + h);
        if (seg == 0) {
#pragma unroll
          for (int j = 0; j < 4; ++j)
            qb[(bhi * 2048 + t0 + j) * 64 + d] = f2bf(acc[m][n][j]);
        } else if (seg == 1) {
#pragma unroll
          for (int j = 0; j < 4; ++j)
            kb[(bhi * 2048 + t0 + j) * 64 + d] = f2bf(acc[m][n][j]);
        } else {
          ushort4 pk;
          pk.x = f2bf(acc[m][n][0]);
          pk.y = f2bf(acc[m][n][1]);
          pk.z = f2bf(acc[m][n][2]);
          pk.w = f2bf(acc[m][n][3]);
          *(ushort4*)(vb + (bhi * 64 + d) * 2048 + t0) = pk;  // V^T [BH][64][T]
        }
      }
    }
  }
}

// ------------------------------------------------------------- attention
// Q,K: [BH][2048][64] bf16.  Vt: [BH][64][2048] bf16.  Ab out: [B][T][H*64] bf16.
// Block bid: qt = 31 - bid/64 (longest-first), bh = bid & 63.
// 4 independent waves; wave w owns q rows [qt*64 + w*16, +16).
// Swapped QK^T: S^T = mfma(K_frag, Q_frag) -> lane (lhi,l15) holds, for q-row
// l15, the 16 key values {kt*16+lhi*4+j}. Softmax entirely in-register
// (max/sum in-lane + shfl_xor 16/32); m,l state in registers. P packed bf16
// through one LDS trip (fragment transpose for the PV A-operand).
__global__ __launch_bounds__(256) void attn_kernel(
    const ushort* __restrict__ Qb, const ushort* __restrict__ Kb,
    const ushort* __restrict__ Vt, ushort* __restrict__ Ab) {
  const int bid = blockIdx.x;
  const int qt = 31 - (bid >> 6);
  const int bh = bid & 63;
  const int tid = threadIdx.x;
  const int lane = tid & 63;
  const int w = tid >> 6;
  const int l15 = lane & 15, lhi = lane >> 4;
  const int qloc = qt * 64 + w * 16;

  __shared__ ushort P[4][16][72];  // 9.2 KB; row stride 144B (16B-aligned)

  const size_t qkbase = (size_t)bh * (2048 * 64);
  const size_t vtb = (size_t)bh * (64 * 2048);

  bf16x8 qf[2];
#pragma unroll
  for (int kk = 0; kk < 2; ++kk)
    qf[kk] = *(const bf16x8*)(Qb + qkbase + (size_t)(qloc + l15) * 64 + kk * 32 + lhi * 8);

  float m_state = -INFINITY, l_state = 0.f;
  f32x4 o[4] = {};
  const float scale = 0.125f;  // 1/sqrt(64)
  const int qrow = qloc + l15;

  for (int kbt = 0; kbt <= qt; ++kbt) {
    const int key0 = kbt * 64;

    // ---- S^T = K Q^T : lane holds q-col l15, key rows kt*16+lhi*4+j
    f32x4 s[4];
#pragma unroll
    for (int kt = 0; kt < 4; ++kt) {
      const ushort* kp = Kb + qkbase + (size_t)(key0 + kt * 16 + l15) * 64 + lhi * 8;
      bf16x8 kf0 = *(const bf16x8*)kp;
      bf16x8 kf1 = *(const bf16x8*)(kp + 32);
      f32x4 acc = {};
      acc = MFMA_BF16(kf0, qf[0], acc);
      acc = MFMA_BF16(kf1, qf[1], acc);
      s[kt] = acc;
    }

    // ---- mask + scale + in-register row max (all 16 values are q-row l15)
    float mloc = m_state;
#pragma unroll
    for (int kt = 0; kt < 4; ++kt)
#pragma unroll
      for (int j = 0; j < 4; ++j) {
        const int key = key0 + kt * 16 + lhi * 4 + j;
        float v = s[kt][j] * scale;
        v = (key > qrow) ? -INFINITY : v;
        s[kt][j] = v;
        mloc = fmaxf(mloc, v);
      }
    mloc = fmaxf(mloc, __shfl_xor(mloc, 16));
    mloc = fmaxf(mloc, __shfl_xor(mloc, 32));
    const float mnew = mloc;                    // already includes m_state
    const float alpha = __expf(m_state - mnew); // first tile: exp(-inf)=0

    // ---- exp + row-sum + pack P -> LDS (P[q=l15][key-local])
    float lloc = 0.f;
#pragma unroll
    for (int kt = 0; kt < 4; ++kt) {
      float p0 = __expf(s[kt][0] - mnew);
      float p1 = __expf(s[kt][1] - mnew);
      float p2 = __expf(s[kt][2] - mnew);
      float p3 = __expf(s[kt][3] - mnew);
      lloc += (p0 + p1) + (p2 + p3);
      uint2 pk;
      pk.x = cvt_pk_bf16(p0, p1);
      pk.y = cvt_pk_bf16(p2, p3);
      *(uint2*)&P[w][l15][kt * 16 + lhi * 4] = pk;
    }
    lloc += __shfl_xor(lloc, 16);
    lloc += __shfl_xor(lloc, 32);
    l_state = l_state * alpha + lloc;
    m_state = mnew;

    asm volatile("s_waitcnt lgkmcnt(0)" ::: "memory");

    // ---- rescale O (rows lhi*4+j) by that row's alpha (lives at lane=row)
    float a_[4];
#pragma unroll
    for (int j = 0; j < 4; ++j) a_[j] = __shfl(alpha, lhi * 4 + j);
#pragma unroll
    for (int n = 0; n < 4; ++n)
#pragma unroll
      for (int j = 0; j < 4; ++j) o[n][j] *= a_[j];

    // ---- O += P V  (A-frag: P rows from LDS; B-frag: Vt rows contiguous)
#pragma unroll
    for (int n = 0; n < 4; ++n) {
#pragma unroll
      for (int ks = 0; ks < 2; ++ks) {
        bf16x8 pf = *(const bf16x8*)&P[w][l15][ks * 32 + lhi * 8];
        bf16x8 vf = *(const bf16x8*)(Vt + vtb + (size_t)(n * 16 + l15) * 2048 + key0 + ks * 32 + lhi * 8);
        o[n] = MFMA_BF16(pf, vf, o[n]);
      }
    }
  }

  // ---- epilogue: normalize by l (state lives at lane=row), store bf16
  float linv[4];
#pragma unroll
  for (int j = 0; j < 4; ++j)
    linv[j] = 1.0f / __shfl(l_state, lhi * 4 + j);
  const int b_ = bh >> 4, h_ = bh & 15;
#pragma unroll
  for (int j = 0; j < 4; ++j) {
    const int t = qloc + lhi * 4 + j;
    const size_t ro = ((size_t)b_ * 2048 + t) * 1024 + h_ * 64;
#pragma unroll
    for (int n = 0; n < 4; ++n)
      Ab[ro + n * 16 + l15] = f2bf(o[n][j] * linv[j]);
  }
}

// ---------------------------------------------------------------- launch
extern "C" void kernel_launch(void* const* d_in, const int* in_sizes, int n_in,
                              void* d_out, int out_size, void* d_ws, size_t ws_size,
                              hipStream_t stream) {
  const float* x = (const float*)d_in[0];
  const float* Wqkv = (const float*)d_in[1];
  const float* Wout = (const float*)d_in[2];
  float* out = (float*)d_out;

  // workspace layout (bf16 elements), total ~88 MB
  ushort* xb    = (ushort*)d_ws;                     // [8192][1024]
  ushort* wqkvT = xb + (size_t)8192 * 1024;          // [3072][1024]
  ushort* woutT = wqkvT + (size_t)3072 * 1024;       // [1024][1024]
  ushort* qb    = woutT + (size_t)1024 * 1024;       // [64][2048][64]
  ushort* kbuf  = qb + (size_t)64 * 2048 * 64;       // [64][2048][64]
  ushort* vbuf  = kbuf + (size_t)64 * 2048 * 64;     // [64][64][2048] (V^T)
  ushort* ab    = vbuf + (size_t)64 * 2048 * 64;     // [8192][1024]

  convert_f32_bf16<<<8192, 256, 0, stream>>>(x, xb, 8192 * 1024 / 4);
  transpose_w<<<dim3(96, 32), 256, 0, stream>>>(Wqkv, wqkvT, 1024, 3072);
  transpose_w<<<dim3(32, 32), 256, 0, stream>>>(Wout, woutT, 1024, 1024);
  gemm_bf16_kernel<0><<<dim3(64, 24), 256, 0, stream>>>(
      xb, wqkvT, nullptr, qb, kbuf, vbuf, 8192, 3072, 1024);
  attn_kernel<<<2048, 256, 0, stream>>>(qb, kbuf, vbuf, ab);
  gemm_bf16_kernel<1><<<dim3(64, 8), 256, 0, stream>>>(
      ab, woutT, out, nullptr, nullptr, nullptr, 8192, 1024, 1024);
}

// Round 3
// 254.200 us; speedup vs baseline: 2.2522x; 1.3991x over previous
//
#include <hip/hip_runtime.h>
#include <hip/hip_bf16.h>
#include <cstdint>

// Causal self-attention: x[4,2048,1024] @ Wqkv[1024,3072] -> QKV -> 16-head
// causal attention (HD=64) -> @ Wout[1024,1024] -> out fp32.
// R3: attention adds cooperative double-buffered LDS staging of K/V tiles
// (reg-staged, prefetch issued at top of iter -> latency hidden under compute),
// XOR-swizzled LDS layout (slot ^= row&7) for conflict-free ds_read_b128,
// s_setprio(1) around MFMA clusters. Softmax stays fully in-register
// (swapped QK^T). One barrier per iteration.

typedef __attribute__((ext_vector_type(8))) short bf16x8;
typedef __attribute__((ext_vector_type(4))) float f32x4;

#define MFMA_BF16(a, b, c) __builtin_amdgcn_mfma_f32_16x16x32_bf16((a), (b), (c), 0, 0, 0)

__device__ __forceinline__ ushort f2bf(float f) {
  union { float f; uint32_t u; } x;
  x.f = f;
  uint32_t u = x.u;
  return (ushort)((u + 0x7FFFu + ((u >> 16) & 1u)) >> 16);
}

__device__ __forceinline__ uint32_t cvt_pk_bf16(float lo, float hi) {
  uint32_t r;
  asm("v_cvt_pk_bf16_f32 %0, %1, %2" : "=v"(r) : "v"(lo), "v"(hi));
  return r;
}

// ---------------------------------------------------------------- convert x
__global__ __launch_bounds__(256) void convert_f32_bf16(
    const float* __restrict__ in, ushort* __restrict__ out, int n4) {
  int i = blockIdx.x * 256 + threadIdx.x;
  if (i < n4) {
    float4 v = ((const float4*)in)[i];
    ushort4 o;
    o.x = f2bf(v.x); o.y = f2bf(v.y); o.z = f2bf(v.z); o.w = f2bf(v.w);
    ((ushort4*)out)[i] = o;
  }
}

// ------------------------------------------------- W [K][N] f32 -> Wt [N][K] bf16
__global__ __launch_bounds__(256) void transpose_w(
    const float* __restrict__ W, ushort* __restrict__ Wt, int K, int N) {
  __shared__ float tile[32][33];
  const int n0 = blockIdx.x * 32, k0 = blockIdx.y * 32;
  const int tx = threadIdx.x & 31, ty = threadIdx.x >> 5;  // ty 0..7
#pragma unroll
  for (int i = 0; i < 4; ++i)
    tile[ty + i * 8][tx] = W[(size_t)(k0 + ty + i * 8) * N + n0 + tx];
  __syncthreads();
#pragma unroll
  for (int i = 0; i < 4; ++i)
    Wt[(size_t)(n0 + ty + i * 8) * K + k0 + tx] = f2bf(tile[tx][ty + i * 8]);
}

// ---------------------------------------------------------------- GEMM bf16
// A [M][K] bf16 row-major, Bt [N][K] bf16 row-major (B transposed).
// MODE 0: epilogue splits QKV -> q,k [BH][T][64] bf16, v transposed [BH][64][T].
// MODE 1: epilogue stores fp32 C [M][N].
template <int MODE>
__global__ __launch_bounds__(256) void gemm_bf16_kernel(
    const ushort* __restrict__ A, const ushort* __restrict__ Bt,
    float* __restrict__ C,
    ushort* __restrict__ qb, ushort* __restrict__ kb, ushort* __restrict__ vb,
    int M, int N, int K) {
  __shared__ ushort As[128][40];  // pad 40: 80B row stride, 16B aligned
  __shared__ ushort Bs[128][40];
  const int tid = threadIdx.x;
  const int lane = tid & 63;
  const int w = tid >> 6;
  const int wr = w >> 1, wc = w & 1;
  const int l15 = lane & 15, lhi = lane >> 4;
  const int row0 = blockIdx.x * 128, col0 = blockIdx.y * 128;
  const int ar = tid >> 2;
  const int ac = (tid & 3) << 3;

  f32x4 acc[4][4] = {};

  for (int k0 = 0; k0 < K; k0 += 32) {
    *(bf16x8*)&As[ar][ac]      = *(const bf16x8*)(A  + (size_t)(row0 + ar) * K + k0 + ac);
    *(bf16x8*)&As[ar + 64][ac] = *(const bf16x8*)(A  + (size_t)(row0 + ar + 64) * K + k0 + ac);
    *(bf16x8*)&Bs[ar][ac]      = *(const bf16x8*)(Bt + (size_t)(col0 + ar) * K + k0 + ac);
    *(bf16x8*)&Bs[ar + 64][ac] = *(const bf16x8*)(Bt + (size_t)(col0 + ar + 64) * K + k0 + ac);
    __syncthreads();
    bf16x8 af[4], bfr[4];
#pragma unroll
    for (int m = 0; m < 4; ++m)
      af[m] = *(const bf16x8*)&As[wr * 64 + m * 16 + l15][lhi * 8];
#pragma unroll
    for (int n = 0; n < 4; ++n)
      bfr[n] = *(const bf16x8*)&Bs[wc * 64 + n * 16 + l15][lhi * 8];
#pragma unroll
    for (int m = 0; m < 4; ++m)
#pragma unroll
      for (int n = 0; n < 4; ++n)
        acc[m][n] = MFMA_BF16(af[m], bfr[n], acc[m][n]);
    __syncthreads();
  }

  if (MODE == 1) {
#pragma unroll
    for (int m = 0; m < 4; ++m) {
      const int r0 = row0 + wr * 64 + m * 16 + lhi * 4;
#pragma unroll
      for (int n = 0; n < 4; ++n) {
        const int c = col0 + wc * 64 + n * 16 + l15;
#pragma unroll
        for (int j = 0; j < 4; ++j)
          C[(size_t)(r0 + j) * N + c] = acc[m][n][j];
      }
    }
  } else {
    // QKV split epilogue. c in [0,3072): seg = c/1024 (q/k/v), h = (c%1024)/64, d = c%64
#pragma unroll
    for (int m = 0; m < 4; ++m) {
      const int r0 = row0 + wr * 64 + m * 16 + lhi * 4;  // global token row (4 consecutive)
      const int b_ = r0 >> 11;
      const int t0 = r0 & 2047;
#pragma unroll
      for (int n = 0; n < 4; ++n) {
        const int c = col0 + wc * 64 + n * 16 + l15;
        const int seg = c >> 10;
        const int cc = c & 1023;
        const int h = cc >> 6, d = cc & 63;
        const size_t bhi = (size_t)(b_ * 16 + h);
        if (seg == 0) {
#pragma unroll
          for (int j = 0; j < 4; ++j)
            qb[(bhi * 2048 + t0 + j) * 64 + d] = f2bf(acc[m][n][j]);
        } else if (seg == 1) {
#pragma unroll
          for (int j = 0; j < 4; ++j)
            kb[(bhi * 2048 + t0 + j) * 64 + d] = f2bf(acc[m][n][j]);
        } else {
          ushort4 pk;
          pk.x = f2bf(acc[m][n][0]);
          pk.y = f2bf(acc[m][n][1]);
          pk.z = f2bf(acc[m][n][2]);
          pk.w = f2bf(acc[m][n][3]);
          *(ushort4*)(vb + (bhi * 64 + d) * 2048 + t0) = pk;  // V^T [BH][64][T]
        }
      }
    }
  }
}

// ------------------------------------------------------------- attention
// Q,K: [BH][2048][64] bf16.  Vt: [BH][64][2048] bf16.  Ab out: [B][T][H*64] bf16.
// Block bid: qt = 31 - bid/64 (longest-first), bh = bid & 63.
// 4 waves; wave w owns q rows [qt*64 + w*16, +16). K/V tiles (64x64 bf16)
// cooperatively staged in LDS, double-buffered, XOR-swizzled (slot ^= row&7).
// Prefetch for tile t+1 issued to regs at top of iter t; ds_write at end;
// one barrier per iteration. Swapped QK^T -> in-register softmax.
__global__ __launch_bounds__(256) void attn_kernel(
    const ushort* __restrict__ Qb, const ushort* __restrict__ Kb,
    const ushort* __restrict__ Vt, ushort* __restrict__ Ab) {
  const int bid = blockIdx.x;
  const int qt = 31 - (bid >> 6);
  const int bh = bid & 63;
  const int tid = threadIdx.x;
  const int lane = tid & 63;
  const int w = tid >> 6;
  const int l15 = lane & 15, lhi = lane >> 4;
  const int qloc = qt * 64 + w * 16;

  __shared__ ushort Ks[2][64 * 64];  // swizzled [key][d]: elem = key*64 + ((d/8)^(key&7))*8 + d%8
  __shared__ ushort Vs[2][64 * 64];  // swizzled [d][key]: elem = d*64 + ((k/8)^(d&7))*8 + k%8
  __shared__ ushort P[4][16][72];    // per-wave P transpose staging (144B rows)

  const size_t qkbase = (size_t)bh * (2048 * 64);
  const size_t vtb = (size_t)bh * (64 * 2048);

  // staging geometry: wave w covers tile rows [w*16, w*16+16), 2 chunks of 8 rows
  const int srow = w * 16 + (lane >> 3);  // + j*8
  const int sd0 = lane & 7;               // 16B slot within 128B row

  bf16x8 qf[2];
#pragma unroll
  for (int kk = 0; kk < 2; ++kk)
    qf[kk] = *(const bf16x8*)(Qb + qkbase + (size_t)(qloc + l15) * 64 + kk * 32 + lhi * 8);

  // ---- prologue: stage tile 0
  uint4 kreg[2], vreg[2];
#pragma unroll
  for (int j = 0; j < 2; ++j) {
    const int row = srow + j * 8;
    kreg[j] = *(const uint4*)(Kb + qkbase + (size_t)row * 64 + sd0 * 8);
    vreg[j] = *(const uint4*)(Vt + vtb + (size_t)row * 2048 + sd0 * 8);
  }
#pragma unroll
  for (int j = 0; j < 2; ++j) {
    const int row = srow + j * 8;
    const int slot = (sd0 ^ (row & 7)) * 8;
    *(uint4*)&Ks[0][row * 64 + slot] = kreg[j];
    *(uint4*)&Vs[0][row * 64 + slot] = vreg[j];
  }
  __syncthreads();

  float m_state = -INFINITY, l_state = 0.f;
  f32x4 o[4] = {};
  const float scale = 0.125f;  // 1/sqrt(64)
  const int qrow = qloc + l15;
  int cur = 0;

  for (int kbt = 0; kbt <= qt; ++kbt) {
    const int key0 = kbt * 64;
    const bool pre = (kbt < qt);  // block-uniform

    // ---- issue prefetch loads for tile kbt+1 (latency hides under compute)
    if (pre) {
      const int nk0 = key0 + 64;
#pragma unroll
      for (int j = 0; j < 2; ++j) {
        const int row = srow + j * 8;
        kreg[j] = *(const uint4*)(Kb + qkbase + (size_t)(nk0 + row) * 64 + sd0 * 8);
        vreg[j] = *(const uint4*)(Vt + vtb + (size_t)row * 2048 + nk0 + sd0 * 8);
      }
    }

    // ---- S^T = K Q^T from LDS (lane: q-col l15, key rows kt*16+lhi*4+j)
    f32x4 s[4];
    __builtin_amdgcn_s_setprio(1);
#pragma unroll
    for (int kt = 0; kt < 4; ++kt) {
      const int krow = kt * 16 + l15;
      const int sw = krow & 7;
      bf16x8 kf0 = *(const bf16x8*)&Ks[cur][krow * 64 + ((lhi ^ sw) * 8)];
      bf16x8 kf1 = *(const bf16x8*)&Ks[cur][krow * 64 + (((4 + lhi) ^ sw) * 8)];
      f32x4 acc = {};
      acc = MFMA_BF16(kf0, qf[0], acc);
      acc = MFMA_BF16(kf1, qf[1], acc);
      s[kt] = acc;
    }
    __builtin_amdgcn_s_setprio(0);

    // ---- mask + scale + in-register row max
    float mloc = m_state;
#pragma unroll
    for (int kt = 0; kt < 4; ++kt)
#pragma unroll
      for (int j = 0; j < 4; ++j) {
        const int key = key0 + kt * 16 + lhi * 4 + j;
        float v = s[kt][j] * scale;
        v = (key > qrow) ? -INFINITY : v;
        s[kt][j] = v;
        mloc = fmaxf(mloc, v);
      }
    mloc = fmaxf(mloc, __shfl_xor(mloc, 16));
    mloc = fmaxf(mloc, __shfl_xor(mloc, 32));
    const float mnew = mloc;                    // includes m_state
    const float alpha = __expf(m_state - mnew); // first tile: exp(-inf)=0

    // ---- exp + row-sum + pack P -> LDS (P[q=l15][key-local])
    float lloc = 0.f;
#pragma unroll
    for (int kt = 0; kt < 4; ++kt) {
      float p0 = __expf(s[kt][0] - mnew);
      float p1 = __expf(s[kt][1] - mnew);
      float p2 = __expf(s[kt][2] - mnew);
      float p3 = __expf(s[kt][3] - mnew);
      lloc += (p0 + p1) + (p2 + p3);
      uint2 pk;
      pk.x = cvt_pk_bf16(p0, p1);
      pk.y = cvt_pk_bf16(p2, p3);
      *(uint2*)&P[w][l15][kt * 16 + lhi * 4] = pk;
    }
    lloc += __shfl_xor(lloc, 16);
    lloc += __shfl_xor(lloc, 32);
    l_state = l_state * alpha + lloc;
    m_state = mnew;

    asm volatile("s_waitcnt lgkmcnt(0)" ::: "memory");

    // ---- rescale O (rows lhi*4+j) by that row's alpha (lives at lane=row)
    float a_[4];
#pragma unroll
    for (int j = 0; j < 4; ++j) a_[j] = __shfl(alpha, lhi * 4 + j);
#pragma unroll
    for (int n = 0; n < 4; ++n)
#pragma unroll
      for (int j = 0; j < 4; ++j) o[n][j] *= a_[j];

    // ---- O += P V from LDS
    __builtin_amdgcn_s_setprio(1);
#pragma unroll
    for (int n = 0; n < 4; ++n) {
      const int vrow = n * 16 + l15;
      const int sw = vrow & 7;
#pragma unroll
      for (int ks = 0; ks < 2; ++ks) {
        bf16x8 pf = *(const bf16x8*)&P[w][l15][ks * 32 + lhi * 8];
        bf16x8 vf = *(const bf16x8*)&Vs[cur][vrow * 64 + (((ks * 4 + lhi) ^ sw) * 8)];
        o[n] = MFMA_BF16(pf, vf, o[n]);
      }
    }
    __builtin_amdgcn_s_setprio(0);

    // ---- commit prefetched tile to the other buffer; one barrier per iter
    if (pre) {
      const int nxt = cur ^ 1;
#pragma unroll
      for (int j = 0; j < 2; ++j) {
        const int row = srow + j * 8;
        const int slot = (sd0 ^ (row & 7)) * 8;
        *(uint4*)&Ks[nxt][row * 64 + slot] = kreg[j];
        *(uint4*)&Vs[nxt][row * 64 + slot] = vreg[j];
      }
      cur = nxt;
      __syncthreads();
    }
  }

  // ---- epilogue: normalize by l (state lives at lane=row), store bf16
  float linv[4];
#pragma unroll
  for (int j = 0; j < 4; ++j)
    linv[j] = 1.0f / __shfl(l_state, lhi * 4 + j);
  const int b_ = bh >> 4, h_ = bh & 15;
#pragma unroll
  for (int j = 0; j < 4; ++j) {
    const int t = qloc + lhi * 4 + j;
    const size_t ro = ((size_t)b_ * 2048 + t) * 1024 + h_ * 64;
#pragma unroll
    for (int n = 0; n < 4; ++n)
      Ab[ro + n * 16 + l15] = f2bf(o[n][j] * linv[j]);
  }
}

// ---------------------------------------------------------------- launch
extern "C" void kernel_launch(void* const* d_in, const int* in_sizes, int n_in,
                              void* d_out, int out_size, void* d_ws, size_t ws_size,
                              hipStream_t stream) {
  const float* x = (const float*)d_in[0];
  const float* Wqkv = (const float*)d_in[1];
  const float* Wout = (const float*)d_in[2];
  float* out = (float*)d_out;

  // workspace layout (bf16 elements), total ~88 MB
  ushort* xb    = (ushort*)d_ws;                     // [8192][1024]
  ushort* wqkvT = xb + (size_t)8192 * 1024;          // [3072][1024]
  ushort* woutT = wqkvT + (size_t)3072 * 1024;       // [1024][1024]
  ushort* qb    = woutT + (size_t)1024 * 1024;       // [64][2048][64]
  ushort* kbuf  = qb + (size_t)64 * 2048 * 64;       // [64][2048][64]
  ushort* vbuf  = kbuf + (size_t)64 * 2048 * 64;     // [64][64][2048] (V^T)
  ushort* ab    = vbuf + (size_t)64 * 2048 * 64;     // [8192][1024]

  convert_f32_bf16<<<8192, 256, 0, stream>>>(x, xb, 8192 * 1024 / 4);
  transpose_w<<<dim3(96, 32), 256, 0, stream>>>(Wqkv, wqkvT, 1024, 3072);
  transpose_w<<<dim3(32, 32), 256, 0, stream>>>(Wout, woutT, 1024, 1024);
  gemm_bf16_kernel<0><<<dim3(64, 24), 256, 0, stream>>>(
      xb, wqkvT, nullptr, qb, kbuf, vbuf, 8192, 3072, 1024);
  attn_kernel<<<2048, 256, 0, stream>>>(qb, kbuf, vbuf, ab);
  gemm_bf16_kernel<1><<<dim3(64, 8), 256, 0, stream>>>(
      ab, woutT, out, nullptr, nullptr, nullptr, 8192, 1024, 1024);
}

// Round 4
// 235.722 us; speedup vs baseline: 2.4287x; 1.0784x over previous
//
#include <hip/hip_runtime.h>
#include <hip/hip_bf16.h>
#include <cstdint>

// Causal self-attention: x[4,2048,1024] @ Wqkv[1024,3072] -> QKV -> 16-head
// causal attention (HD=64) -> @ Wout[1024,1024] -> out fp32.
// R4: VALU-diet softmax. Q pre-scaled by 0.125*log2(e) in the QKV epilogue ->
// softmax in exp2 domain (bare v_exp_f32); causal mask applied only on the
// final (diagonal) k-tile; defer-max rescale (THR=8, log2 domain) skips the
// O-rescale pass on most tiles. K/V LDS staging double-buffered + XOR-swizzled
// as in R3; swapped QK^T keeps softmax fully in-register.

typedef __attribute__((ext_vector_type(8))) short bf16x8;
typedef __attribute__((ext_vector_type(4))) float f32x4;

#define MFMA_BF16(a, b, c) __builtin_amdgcn_mfma_f32_16x16x32_bf16((a), (b), (c), 0, 0, 0)

__device__ __forceinline__ ushort f2bf(float f) {
  union { float f; uint32_t u; } x;
  x.f = f;
  uint32_t u = x.u;
  return (ushort)((u + 0x7FFFu + ((u >> 16) & 1u)) >> 16);
}

__device__ __forceinline__ uint32_t cvt_pk_bf16(float lo, float hi) {
  uint32_t r;
  asm("v_cvt_pk_bf16_f32 %0, %1, %2" : "=v"(r) : "v"(lo), "v"(hi));
  return r;
}

// ---------------------------------------------------------------- convert x
__global__ __launch_bounds__(256) void convert_f32_bf16(
    const float* __restrict__ in, ushort* __restrict__ out, int n4) {
  int i = blockIdx.x * 256 + threadIdx.x;
  if (i < n4) {
    float4 v = ((const float4*)in)[i];
    ushort4 o;
    o.x = f2bf(v.x); o.y = f2bf(v.y); o.z = f2bf(v.z); o.w = f2bf(v.w);
    ((ushort4*)out)[i] = o;
  }
}

// ------------------------------------------------- W [K][N] f32 -> Wt [N][K] bf16
__global__ __launch_bounds__(256) void transpose_w(
    const float* __restrict__ W, ushort* __restrict__ Wt, int K, int N) {
  __shared__ float tile[32][33];
  const int n0 = blockIdx.x * 32, k0 = blockIdx.y * 32;
  const int tx = threadIdx.x & 31, ty = threadIdx.x >> 5;  // ty 0..7
#pragma unroll
  for (int i = 0; i < 4; ++i)
    tile[ty + i * 8][tx] = W[(size_t)(k0 + ty + i * 8) * N + n0 + tx];
  __syncthreads();
#pragma unroll
  for (int i = 0; i < 4; ++i)
    Wt[(size_t)(n0 + ty + i * 8) * K + k0 + tx] = f2bf(tile[tx][ty + i * 8]);
}

// ---------------------------------------------------------------- GEMM bf16
// A [M][K] bf16 row-major, Bt [N][K] bf16 row-major (B transposed).
// MODE 0: epilogue splits QKV -> q (pre-scaled by 0.125*log2e), k [BH][T][64]
//         bf16, v transposed [BH][64][T].
// MODE 1: epilogue stores fp32 C [M][N].
template <int MODE>
__global__ __launch_bounds__(256) void gemm_bf16_kernel(
    const ushort* __restrict__ A, const ushort* __restrict__ Bt,
    float* __restrict__ C,
    ushort* __restrict__ qb, ushort* __restrict__ kb, ushort* __restrict__ vb,
    int M, int N, int K) {
  __shared__ ushort As[128][40];  // pad 40: 80B row stride, 16B aligned
  __shared__ ushort Bs[128][40];
  const int tid = threadIdx.x;
  const int lane = tid & 63;
  const int w = tid >> 6;
  const int wr = w >> 1, wc = w & 1;
  const int l15 = lane & 15, lhi = lane >> 4;
  const int row0 = blockIdx.x * 128, col0 = blockIdx.y * 128;
  const int ar = tid >> 2;
  const int ac = (tid & 3) << 3;

  f32x4 acc[4][4] = {};

  for (int k0 = 0; k0 < K; k0 += 32) {
    *(bf16x8*)&As[ar][ac]      = *(const bf16x8*)(A  + (size_t)(row0 + ar) * K + k0 + ac);
    *(bf16x8*)&As[ar + 64][ac] = *(const bf16x8*)(A  + (size_t)(row0 + ar + 64) * K + k0 + ac);
    *(bf16x8*)&Bs[ar][ac]      = *(const bf16x8*)(Bt + (size_t)(col0 + ar) * K + k0 + ac);
    *(bf16x8*)&Bs[ar + 64][ac] = *(const bf16x8*)(Bt + (size_t)(col0 + ar + 64) * K + k0 + ac);
    __syncthreads();
    bf16x8 af[4], bfr[4];
#pragma unroll
    for (int m = 0; m < 4; ++m)
      af[m] = *(const bf16x8*)&As[wr * 64 + m * 16 + l15][lhi * 8];
#pragma unroll
    for (int n = 0; n < 4; ++n)
      bfr[n] = *(const bf16x8*)&Bs[wc * 64 + n * 16 + l15][lhi * 8];
#pragma unroll
    for (int m = 0; m < 4; ++m)
#pragma unroll
      for (int n = 0; n < 4; ++n)
        acc[m][n] = MFMA_BF16(af[m], bfr[n], acc[m][n]);
    __syncthreads();
  }

  if (MODE == 1) {
#pragma unroll
    for (int m = 0; m < 4; ++m) {
      const int r0 = row0 + wr * 64 + m * 16 + lhi * 4;
#pragma unroll
      for (int n = 0; n < 4; ++n) {
        const int c = col0 + wc * 64 + n * 16 + l15;
#pragma unroll
        for (int j = 0; j < 4; ++j)
          C[(size_t)(r0 + j) * N + c] = acc[m][n][j];
      }
    }
  } else {
    // QKV split epilogue. c in [0,3072): seg = c/1024 (q/k/v), h = (c%1024)/64, d = c%64
    const float QSCALE = 0.18033688011112042f;  // (1/sqrt(64)) * log2(e)
#pragma unroll
    for (int m = 0; m < 4; ++m) {
      const int r0 = row0 + wr * 64 + m * 16 + lhi * 4;  // global token row (4 consecutive)
      const int b_ = r0 >> 11;
      const int t0 = r0 & 2047;
#pragma unroll
      for (int n = 0; n < 4; ++n) {
        const int c = col0 + wc * 64 + n * 16 + l15;
        const int seg = c >> 10;
        const int cc = c & 1023;
        const int h = cc >> 6, d = cc & 63;
        const size_t bhi = (size_t)(b_ * 16 + h);
        if (seg == 0) {
#pragma unroll
          for (int j = 0; j < 4; ++j)
            qb[(bhi * 2048 + t0 + j) * 64 + d] = f2bf(acc[m][n][j] * QSCALE);
        } else if (seg == 1) {
#pragma unroll
          for (int j = 0; j < 4; ++j)
            kb[(bhi * 2048 + t0 + j) * 64 + d] = f2bf(acc[m][n][j]);
        } else {
          ushort4 pk;
          pk.x = f2bf(acc[m][n][0]);
          pk.y = f2bf(acc[m][n][1]);
          pk.z = f2bf(acc[m][n][2]);
          pk.w = f2bf(acc[m][n][3]);
          *(ushort4*)(vb + (bhi * 64 + d) * 2048 + t0) = pk;  // V^T [BH][64][T]
        }
      }
    }
  }
}

// ------------------------------------------------------------- attention
// Q: [BH][2048][64] bf16 pre-scaled by 0.125*log2e -> scores in exp2 domain.
// K: [BH][2048][64] bf16.  Vt: [BH][64][2048] bf16.  Ab out: [B][T][H*64] bf16.
// Block bid: qt = 31 - bid/64 (longest-first), bh = bid & 63.
// 4 waves; wave w owns q rows [qt*64 + w*16, +16). K/V tiles (64x64 bf16)
// cooperatively staged in LDS, double-buffered, XOR-swizzled (slot ^= row&7).
// Swapped QK^T -> in-register softmax; mask only on diagonal tile; defer-max
// (THR=8 in log2 domain) skips O-rescale on most tiles.
__global__ __launch_bounds__(256) void attn_kernel(
    const ushort* __restrict__ Qb, const ushort* __restrict__ Kb,
    const ushort* __restrict__ Vt, ushort* __restrict__ Ab) {
  const int bid = blockIdx.x;
  const int qt = 31 - (bid >> 6);
  const int bh = bid & 63;
  const int tid = threadIdx.x;
  const int lane = tid & 63;
  const int w = tid >> 6;
  const int l15 = lane & 15, lhi = lane >> 4;
  const int qloc = qt * 64 + w * 16;

  __shared__ ushort Ks[2][64 * 64];  // swizzled [key][d]: elem = key*64 + ((d/8)^(key&7))*8 + d%8
  __shared__ ushort Vs[2][64 * 64];  // swizzled [d][key]: elem = d*64 + ((k/8)^(d&7))*8 + k%8
  __shared__ ushort P[4][16][72];    // per-wave P transpose staging (144B rows)

  const size_t qkbase = (size_t)bh * (2048 * 64);
  const size_t vtb = (size_t)bh * (64 * 2048);

  // staging geometry: wave w covers tile rows [w*16, w*16+16), 2 chunks of 8 rows
  const int srow = w * 16 + (lane >> 3);  // + j*8
  const int sd0 = lane & 7;               // 16B slot within 128B row

  bf16x8 qf[2];
#pragma unroll
  for (int kk = 0; kk < 2; ++kk)
    qf[kk] = *(const bf16x8*)(Qb + qkbase + (size_t)(qloc + l15) * 64 + kk * 32 + lhi * 8);

  // ---- prologue: stage tile 0
  uint4 kreg[2], vreg[2];
#pragma unroll
  for (int j = 0; j < 2; ++j) {
    const int row = srow + j * 8;
    kreg[j] = *(const uint4*)(Kb + qkbase + (size_t)row * 64 + sd0 * 8);
    vreg[j] = *(const uint4*)(Vt + vtb + (size_t)row * 2048 + sd0 * 8);
  }
#pragma unroll
  for (int j = 0; j < 2; ++j) {
    const int row = srow + j * 8;
    const int slot = (sd0 ^ (row & 7)) * 8;
    *(uint4*)&Ks[0][row * 64 + slot] = kreg[j];
    *(uint4*)&Vs[0][row * 64 + slot] = vreg[j];
  }
  __syncthreads();

  float m_state = -INFINITY, l_state = 0.f;
  f32x4 o[4] = {};
  const int qrow = qloc + l15;
  int cur = 0;

  for (int kbt = 0; kbt <= qt; ++kbt) {
    const int key0 = kbt * 64;
    const bool last = (kbt == qt);  // block-uniform

    // ---- issue prefetch loads for tile kbt+1 (latency hides under compute)
    if (!last) {
      const int nk0 = key0 + 64;
#pragma unroll
      for (int j = 0; j < 2; ++j) {
        const int row = srow + j * 8;
        kreg[j] = *(const uint4*)(Kb + qkbase + (size_t)(nk0 + row) * 64 + sd0 * 8);
        vreg[j] = *(const uint4*)(Vt + vtb + (size_t)row * 2048 + nk0 + sd0 * 8);
      }
    }

    // ---- S^T = K Q^T from LDS (lane: q-col l15, key rows kt*16+lhi*4+j)
    f32x4 s[4];
    __builtin_amdgcn_s_setprio(1);
#pragma unroll
    for (int kt = 0; kt < 4; ++kt) {
      const int krow = kt * 16 + l15;
      const int sw = krow & 7;
      bf16x8 kf0 = *(const bf16x8*)&Ks[cur][krow * 64 + ((lhi ^ sw) * 8)];
      bf16x8 kf1 = *(const bf16x8*)&Ks[cur][krow * 64 + (((4 + lhi) ^ sw) * 8)];
      f32x4 acc = {};
      acc = MFMA_BF16(kf0, qf[0], acc);
      acc = MFMA_BF16(kf1, qf[1], acc);
      s[kt] = acc;
    }
    __builtin_amdgcn_s_setprio(0);

    // ---- causal mask: only the diagonal tile needs it (wave-uniform branch)
    if (last) {
#pragma unroll
      for (int kt = 0; kt < 4; ++kt)
#pragma unroll
        for (int j = 0; j < 4; ++j) {
          const int key = key0 + kt * 16 + lhi * 4 + j;
          if (key > qrow) s[kt][j] = -INFINITY;
        }
    }

    // ---- tile max (values already in exp2 domain; no scale mul)
    float t0 = fmaxf(fmaxf(s[0][0], s[0][1]), fmaxf(s[0][2], s[0][3]));
    float t1 = fmaxf(fmaxf(s[1][0], s[1][1]), fmaxf(s[1][2], s[1][3]));
    float t2 = fmaxf(fmaxf(s[2][0], s[2][1]), fmaxf(s[2][2], s[2][3]));
    float t3 = fmaxf(fmaxf(s[3][0], s[3][1]), fmaxf(s[3][2], s[3][3]));
    float tmax = fmaxf(fmaxf(t0, t1), fmaxf(t2, t3));
    tmax = fmaxf(tmax, __shfl_xor(tmax, 16));
    tmax = fmaxf(tmax, __shfl_xor(tmax, 32));

    // ---- defer-max: rescale only when the running max grows by > 8 (2^8 bound)
    if (!__all(tmax <= m_state + 8.0f)) {
      const float mnew = fmaxf(m_state, tmax);
      const float alpha = exp2f(m_state - mnew);  // first tile: exp2(-inf)=0
      float a_[4];
#pragma unroll
      for (int j = 0; j < 4; ++j) a_[j] = __shfl(alpha, lhi * 4 + j);
#pragma unroll
      for (int n = 0; n < 4; ++n)
#pragma unroll
        for (int j = 0; j < 4; ++j) o[n][j] *= a_[j];
      l_state *= alpha;
      m_state = mnew;
    }

    // ---- exp2 + row-sum + pack P -> LDS (P[q=l15][key-local])
    float lloc = 0.f;
#pragma unroll
    for (int kt = 0; kt < 4; ++kt) {
      float p0 = exp2f(s[kt][0] - m_state);
      float p1 = exp2f(s[kt][1] - m_state);
      float p2 = exp2f(s[kt][2] - m_state);
      float p3 = exp2f(s[kt][3] - m_state);
      lloc += (p0 + p1) + (p2 + p3);
      uint2 pk;
      pk.x = cvt_pk_bf16(p0, p1);
      pk.y = cvt_pk_bf16(p2, p3);
      *(uint2*)&P[w][l15][kt * 16 + lhi * 4] = pk;
    }
    lloc += __shfl_xor(lloc, 16);
    lloc += __shfl_xor(lloc, 32);
    l_state += lloc;

    asm volatile("s_waitcnt lgkmcnt(0)" ::: "memory");

    // ---- O += P V from LDS
    __builtin_amdgcn_s_setprio(1);
#pragma unroll
    for (int n = 0; n < 4; ++n) {
      const int vrow = n * 16 + l15;
      const int sw = vrow & 7;
#pragma unroll
      for (int ks = 0; ks < 2; ++ks) {
        bf16x8 pf = *(const bf16x8*)&P[w][l15][ks * 32 + lhi * 8];
        bf16x8 vf = *(const bf16x8*)&Vs[cur][vrow * 64 + (((ks * 4 + lhi) ^ sw) * 8)];
        o[n] = MFMA_BF16(pf, vf, o[n]);
      }
    }
    __builtin_amdgcn_s_setprio(0);

    // ---- commit prefetched tile to the other buffer; one barrier per iter
    if (!last) {
      const int nxt = cur ^ 1;
#pragma unroll
      for (int j = 0; j < 2; ++j) {
        const int row = srow + j * 8;
        const int slot = (sd0 ^ (row & 7)) * 8;
        *(uint4*)&Ks[nxt][row * 64 + slot] = kreg[j];
        *(uint4*)&Vs[nxt][row * 64 + slot] = vreg[j];
      }
      cur = nxt;
      __syncthreads();
    }
  }

  // ---- epilogue: normalize by l (state lives at lane=row), store bf16
  float linv[4];
#pragma unroll
  for (int j = 0; j < 4; ++j)
    linv[j] = 1.0f / __shfl(l_state, lhi * 4 + j);
  const int b_ = bh >> 4, h_ = bh & 15;
#pragma unroll
  for (int j = 0; j < 4; ++j) {
    const int t = qloc + lhi * 4 + j;
    const size_t ro = ((size_t)b_ * 2048 + t) * 1024 + h_ * 64;
#pragma unroll
    for (int n = 0; n < 4; ++n)
      Ab[ro + n * 16 + l15] = f2bf(o[n][j] * linv[j]);
  }
}

// ---------------------------------------------------------------- launch
extern "C" void kernel_launch(void* const* d_in, const int* in_sizes, int n_in,
                              void* d_out, int out_size, void* d_ws, size_t ws_size,
                              hipStream_t stream) {
  const float* x = (const float*)d_in[0];
  const float* Wqkv = (const float*)d_in[1];
  const float* Wout = (const float*)d_in[2];
  float* out = (float*)d_out;

  // workspace layout (bf16 elements), total ~88 MB
  ushort* xb    = (ushort*)d_ws;                     // [8192][1024]
  ushort* wqkvT = xb + (size_t)8192 * 1024;          // [3072][1024]
  ushort* woutT = wqkvT + (size_t)3072 * 1024;       // [1024][1024]
  ushort* qb    = woutT + (size_t)1024 * 1024;       // [64][2048][64]
  ushort* kbuf  = qb + (size_t)64 * 2048 * 64;       // [64][2048][64]
  ushort* vbuf  = kbuf + (size_t)64 * 2048 * 64;     // [64][64][2048] (V^T)
  ushort* ab    = vbuf + (size_t)64 * 2048 * 64;     // [8192][1024]

  convert_f32_bf16<<<8192, 256, 0, stream>>>(x, xb, 8192 * 1024 / 4);
  transpose_w<<<dim3(96, 32), 256, 0, stream>>>(Wqkv, wqkvT, 1024, 3072);
  transpose_w<<<dim3(32, 32), 256, 0, stream>>>(Wout, woutT, 1024, 1024);
  gemm_bf16_kernel<0><<<dim3(64, 24), 256, 0, stream>>>(
      xb, wqkvT, nullptr, qb, kbuf, vbuf, 8192, 3072, 1024);
  attn_kernel<<<2048, 256, 0, stream>>>(qb, kbuf, vbuf, ab);
  gemm_bf16_kernel<1><<<dim3(64, 8), 256, 0, stream>>>(
      ab, woutT, out, nullptr, nullptr, nullptr, 8192, 1024, 1024);
}

// Round 5
// 234.474 us; speedup vs baseline: 2.4416x; 1.0053x over previous
//
#include <hip/hip_runtime.h>
#include <hip/hip_bf16.h>
#include <cstdint>

// Causal self-attention: x[4,2048,1024] @ Wqkv[1024,3072] -> QKV -> 16-head
// causal attention (HD=64) -> @ Wout[1024,1024] -> out fp32.
// R5: (1) GEMMs ported to m97 structure: global_load_lds width=16 into linear
// [128][32] LDS (no reg round-trip). (2) attention: 128-row q-blocks, 4 waves
// x 2 q-subtiles of 16 rows -> K/V staging + barriers amortized 2x, each K/V
// LDS read feeds two MFMA chains, two independent softmax chains per wave.
// Softmax stays in-register (swapped QK^T), exp2 domain, diagonal-only mask,
// defer-max (THR=8).

typedef __attribute__((ext_vector_type(8))) short bf16x8;
typedef __attribute__((ext_vector_type(4))) float f32x4;

#define MFMA_BF16(a, b, c) __builtin_amdgcn_mfma_f32_16x16x32_bf16((a), (b), (c), 0, 0, 0)

__device__ __forceinline__ ushort f2bf(float f) {
  union { float f; uint32_t u; } x;
  x.f = f;
  uint32_t u = x.u;
  return (ushort)((u + 0x7FFFu + ((u >> 16) & 1u)) >> 16);
}

__device__ __forceinline__ uint32_t cvt_pk_bf16(float lo, float hi) {
  uint32_t r;
  asm("v_cvt_pk_bf16_f32 %0, %1, %2" : "=v"(r) : "v"(lo), "v"(hi));
  return r;
}

__device__ __forceinline__ void gload16(const ushort* g, ushort* l) {
  __builtin_amdgcn_global_load_lds(
      (const __attribute__((address_space(1))) void*)g,
      (__attribute__((address_space(3))) void*)l, 16, 0, 0);
}

// ---------------------------------------------------------------- convert x
__global__ __launch_bounds__(256) void convert_f32_bf16(
    const float* __restrict__ in, ushort* __restrict__ out, int n4) {
  int i = blockIdx.x * 256 + threadIdx.x;
  if (i < n4) {
    float4 v = ((const float4*)in)[i];
    ushort4 o;
    o.x = f2bf(v.x); o.y = f2bf(v.y); o.z = f2bf(v.z); o.w = f2bf(v.w);
    ((ushort4*)out)[i] = o;
  }
}

// ------------------------------------------------- W [K][N] f32 -> Wt [N][K] bf16
__global__ __launch_bounds__(256) void transpose_w(
    const float* __restrict__ W, ushort* __restrict__ Wt, int K, int N) {
  __shared__ float tile[32][33];
  const int n0 = blockIdx.x * 32, k0 = blockIdx.y * 32;
  const int tx = threadIdx.x & 31, ty = threadIdx.x >> 5;  // ty 0..7
#pragma unroll
  for (int i = 0; i < 4; ++i)
    tile[ty + i * 8][tx] = W[(size_t)(k0 + ty + i * 8) * N + n0 + tx];
  __syncthreads();
#pragma unroll
  for (int i = 0; i < 4; ++i)
    Wt[(size_t)(n0 + ty + i * 8) * K + k0 + tx] = f2bf(tile[tx][ty + i * 8]);
}

// ---------------------------------------------------------------- GEMM bf16
// A [M][K] bf16 row-major, Bt [N][K] bf16 row-major (B transposed).
// m97 structure: linear LDS [128][32], global_load_lds dwordx4 staging
// (wave-uniform LDS base + lane*16B), 2 barriers per K-step.
// MODE 0: epilogue splits QKV -> q (pre-scaled by 0.125*log2e), k [BH][T][64]
//         bf16, v transposed [BH][64][T].
// MODE 1: epilogue stores fp32 C [M][N].
template <int MODE>
__global__ __launch_bounds__(256) void gemm_bf16_kernel(
    const ushort* __restrict__ A, const ushort* __restrict__ Bt,
    float* __restrict__ C,
    ushort* __restrict__ qb, ushort* __restrict__ kb, ushort* __restrict__ vb,
    int M, int N, int K) {
  __shared__ ushort As[128 * 32];
  __shared__ ushort Bs[128 * 32];
  const int tid = threadIdx.x;
  const int lane = tid & 63;
  const int w = tid >> 6;
  const int wr = w >> 1, wc = w & 1;
  const int l15 = lane & 15, lhi = lane >> 4;
  const int row0 = blockIdx.x * 128, col0 = blockIdx.y * 128;

  // staging geometry: wave w owns chunks {2w, 2w+1}; chunk = 16 rows x 32 cols
  const int ch = w * 2;
  const int lr = lane >> 2;           // row within chunk
  const int lc = (lane & 3) << 3;     // ushort col offset (16B granules)
  const ushort* ga0 = A  + (size_t)(row0 + ch * 16 + lr) * K + lc;
  const ushort* ga1 = A  + (size_t)(row0 + ch * 16 + 16 + lr) * K + lc;
  const ushort* gb0 = Bt + (size_t)(col0 + ch * 16 + lr) * K + lc;
  const ushort* gb1 = Bt + (size_t)(col0 + ch * 16 + 16 + lr) * K + lc;
  ushort* la0 = &As[ch * 512];
  ushort* la1 = &As[(ch + 1) * 512];
  ushort* lb0 = &Bs[ch * 512];
  ushort* lb1 = &Bs[(ch + 1) * 512];

  f32x4 acc[4][4] = {};

  for (int k0 = 0; k0 < K; k0 += 32) {
    gload16(ga0 + k0, la0);
    gload16(ga1 + k0, la1);
    gload16(gb0 + k0, lb0);
    gload16(gb1 + k0, lb1);
    __syncthreads();  // drains vmcnt(0): staged tile visible
    bf16x8 af[4], bfr[4];
#pragma unroll
    for (int m = 0; m < 4; ++m)
      af[m] = *(const bf16x8*)&As[(wr * 64 + m * 16 + l15) * 32 + lhi * 8];
#pragma unroll
    for (int n = 0; n < 4; ++n)
      bfr[n] = *(const bf16x8*)&Bs[(wc * 64 + n * 16 + l15) * 32 + lhi * 8];
    __builtin_amdgcn_s_setprio(1);
#pragma unroll
    for (int m = 0; m < 4; ++m)
#pragma unroll
      for (int n = 0; n < 4; ++n)
        acc[m][n] = MFMA_BF16(af[m], bfr[n], acc[m][n]);
    __builtin_amdgcn_s_setprio(0);
    __syncthreads();  // reads done before next-tile staging
  }

  if (MODE == 1) {
#pragma unroll
    for (int m = 0; m < 4; ++m) {
      const int r0 = row0 + wr * 64 + m * 16 + lhi * 4;
#pragma unroll
      for (int n = 0; n < 4; ++n) {
        const int c = col0 + wc * 64 + n * 16 + l15;
#pragma unroll
        for (int j = 0; j < 4; ++j)
          C[(size_t)(r0 + j) * N + c] = acc[m][n][j];
      }
    }
  } else {
    // QKV split epilogue. c in [0,3072): seg = c/1024 (q/k/v), h = (c%1024)/64, d = c%64
    const float QSCALE = 0.18033688011112042f;  // (1/sqrt(64)) * log2(e)
#pragma unroll
    for (int m = 0; m < 4; ++m) {
      const int r0 = row0 + wr * 64 + m * 16 + lhi * 4;  // global token row (4 consecutive)
      const int b_ = r0 >> 11;
      const int t0 = r0 & 2047;
#pragma unroll
      for (int n = 0; n < 4; ++n) {
        const int c = col0 + wc * 64 + n * 16 + l15;
        const int seg = c >> 10;
        const int cc = c & 1023;
        const int h = cc >> 6, d = cc & 63;
        const size_t bhi = (size_t)(b_ * 16 + h);
        if (seg == 0) {
#pragma unroll
          for (int j = 0; j < 4; ++j)
            qb[(bhi * 2048 + t0 + j) * 64 + d] = f2bf(acc[m][n][j] * QSCALE);
        } else if (seg == 1) {
#pragma unroll
          for (int j = 0; j < 4; ++j)
            kb[(bhi * 2048 + t0 + j) * 64 + d] = f2bf(acc[m][n][j]);
        } else {
          ushort4 pk;
          pk.x = f2bf(acc[m][n][0]);
          pk.y = f2bf(acc[m][n][1]);
          pk.z = f2bf(acc[m][n][2]);
          pk.w = f2bf(acc[m][n][3]);
          *(ushort4*)(vb + (bhi * 64 + d) * 2048 + t0) = pk;  // V^T [BH][64][T]
        }
      }
    }
  }
}

// ------------------------------------------------------------- attention
// Q: [BH][2048][64] bf16 pre-scaled by 0.125*log2e.  K: [BH][2048][64] bf16.
// Vt: [BH][64][2048] bf16.  Ab out: [B][T][H*64] bf16.
// Block bid: qb = 15 - bid/64 (longest-first), bh = bid & 63. 128 q-rows per
// block: wave w, subtile s owns rows qb*128 + s*64 + w*16 .. +16.
// K/V 64x64 tiles staged in LDS (double-buffered, XOR-swizzled); each kf/vf
// LDS read feeds both subtiles' MFMA chains. In-register softmax per subtile.
__global__ __launch_bounds__(256) void attn_kernel(
    const ushort* __restrict__ Qb, const ushort* __restrict__ Kb,
    const ushort* __restrict__ Vt, ushort* __restrict__ Ab) {
  const int bid = blockIdx.x;
  const int qb_ = 15 - (bid >> 6);
  const int bh = bid & 63;
  const int tid = threadIdx.x;
  const int lane = tid & 63;
  const int w = tid >> 6;
  const int l15 = lane & 15, lhi = lane >> 4;
  const int qt2 = qb_ * 2;              // sub0 diagonal k-tile index
  const int qloc0 = qb_ * 128 + w * 16; // sub0 rows
  const int qloc1 = qloc0 + 64;         // sub1 rows

  __shared__ ushort Ks[2][64 * 64];    // swizzled: elem = key*64 + ((d/8)^(key&7))*8 + d%8
  __shared__ ushort Vs[2][64 * 64];    // swizzled: elem = d*64 + ((k/8)^(d&7))*8 + k%8
  __shared__ ushort P[4][2][16][72];   // per-wave, per-subtile P staging

  const size_t qkbase = (size_t)bh * (2048 * 64);
  const size_t vtb = (size_t)bh * (64 * 2048);

  // staging geometry: wave w covers tile rows [w*16, w*16+16)
  const int srow = w * 16 + (lane >> 3);  // + j*8
  const int sd0 = lane & 7;

  bf16x8 qf[2][2];
#pragma unroll
  for (int s = 0; s < 2; ++s)
#pragma unroll
    for (int kk = 0; kk < 2; ++kk)
      qf[s][kk] = *(const bf16x8*)(Qb + qkbase +
                                   (size_t)(qloc0 + s * 64 + l15) * 64 + kk * 32 + lhi * 8);

  // ---- prologue: stage tile 0
  uint4 kreg[2], vreg[2];
#pragma unroll
  for (int j = 0; j < 2; ++j) {
    const int row = srow + j * 8;
    kreg[j] = *(const uint4*)(Kb + qkbase + (size_t)row * 64 + sd0 * 8);
    vreg[j] = *(const uint4*)(Vt + vtb + (size_t)row * 2048 + sd0 * 8);
  }
#pragma unroll
  for (int j = 0; j < 2; ++j) {
    const int row = srow + j * 8;
    const int slot = (sd0 ^ (row & 7)) * 8;
    *(uint4*)&Ks[0][row * 64 + slot] = kreg[j];
    *(uint4*)&Vs[0][row * 64 + slot] = vreg[j];
  }
  __syncthreads();

  float m0 = -INFINITY, l0 = 0.f, m1 = -INFINITY, l1 = 0.f;
  f32x4 o0[4] = {}, o1[4] = {};
  const int qrow0 = qloc0 + l15, qrow1 = qloc1 + l15;
  int cur = 0;
  const int nt = qt2 + 2;  // k-tiles for this q-block

  for (int kbt = 0; kbt < nt; ++kbt) {
    const int key0 = kbt * 64;
    const bool pre = (kbt + 1 < nt);
    const bool do0 = (kbt <= qt2);  // sub0 inactive on the final tile

    // ---- issue prefetch loads for tile kbt+1
    if (pre) {
      const int nk0 = key0 + 64;
#pragma unroll
      for (int j = 0; j < 2; ++j) {
        const int row = srow + j * 8;
        kreg[j] = *(const uint4*)(Kb + qkbase + (size_t)(nk0 + row) * 64 + sd0 * 8);
        vreg[j] = *(const uint4*)(Vt + vtb + (size_t)row * 2048 + nk0 + sd0 * 8);
      }
    }

    // ---- S^T = K Q^T for both subtiles; each kf read feeds 2 chains
    f32x4 s0[4], s1[4];
    __builtin_amdgcn_s_setprio(1);
#pragma unroll
    for (int kt = 0; kt < 4; ++kt) {
      const int krow = kt * 16 + l15;
      const int sw = krow & 7;
      bf16x8 kf0 = *(const bf16x8*)&Ks[cur][krow * 64 + ((lhi ^ sw) * 8)];
      bf16x8 kf1 = *(const bf16x8*)&Ks[cur][krow * 64 + (((4 + lhi) ^ sw) * 8)];
      f32x4 a0 = {}, a1 = {};
      a0 = MFMA_BF16(kf0, qf[0][0], a0);
      a1 = MFMA_BF16(kf0, qf[1][0], a1);
      a0 = MFMA_BF16(kf1, qf[0][1], a0);
      a1 = MFMA_BF16(kf1, qf[1][1], a1);
      s0[kt] = a0;
      s1[kt] = a1;
    }
    __builtin_amdgcn_s_setprio(0);

    // ---- diagonal masks (wave-uniform branches)
    if (kbt == qt2) {
#pragma unroll
      for (int kt = 0; kt < 4; ++kt)
#pragma unroll
        for (int j = 0; j < 4; ++j)
          if (key0 + kt * 16 + lhi * 4 + j > qrow0) s0[kt][j] = -INFINITY;
    }
    if (kbt == qt2 + 1) {
#pragma unroll
      for (int kt = 0; kt < 4; ++kt)
#pragma unroll
        for (int j = 0; j < 4; ++j)
          if (key0 + kt * 16 + lhi * 4 + j > qrow1) s1[kt][j] = -INFINITY;
    }

    // ---- softmax sub0
    if (do0) {
      float t0 = fmaxf(fmaxf(s0[0][0], s0[0][1]), fmaxf(s0[0][2], s0[0][3]));
      float t1 = fmaxf(fmaxf(s0[1][0], s0[1][1]), fmaxf(s0[1][2], s0[1][3]));
      float t2 = fmaxf(fmaxf(s0[2][0], s0[2][1]), fmaxf(s0[2][2], s0[2][3]));
      float t3 = fmaxf(fmaxf(s0[3][0], s0[3][1]), fmaxf(s0[3][2], s0[3][3]));
      float tmax = fmaxf(fmaxf(t0, t1), fmaxf(t2, t3));
      tmax = fmaxf(tmax, __shfl_xor(tmax, 16));
      tmax = fmaxf(tmax, __shfl_xor(tmax, 32));
      if (!__all(tmax <= m0 + 8.0f)) {
        const float mnew = fmaxf(m0, tmax);
        const float alpha = exp2f(m0 - mnew);
        float a_[4];
#pragma unroll
        for (int j = 0; j < 4; ++j) a_[j] = __shfl(alpha, lhi * 4 + j);
#pragma unroll
        for (int n = 0; n < 4; ++n)
#pragma unroll
          for (int j = 0; j < 4; ++j) o0[n][j] *= a_[j];
        l0 *= alpha;
        m0 = mnew;
      }
      float lloc = 0.f;
#pragma unroll
      for (int kt = 0; kt < 4; ++kt) {
        float p0 = exp2f(s0[kt][0] - m0);
        float p1 = exp2f(s0[kt][1] - m0);
        float p2 = exp2f(s0[kt][2] - m0);
        float p3 = exp2f(s0[kt][3] - m0);
        lloc += (p0 + p1) + (p2 + p3);
        uint2 pk;
        pk.x = cvt_pk_bf16(p0, p1);
        pk.y = cvt_pk_bf16(p2, p3);
        *(uint2*)&P[w][0][l15][kt * 16 + lhi * 4] = pk;
      }
      lloc += __shfl_xor(lloc, 16);
      lloc += __shfl_xor(lloc, 32);
      l0 += lloc;
    }

    // ---- softmax sub1 (always active)
    {
      float t0 = fmaxf(fmaxf(s1[0][0], s1[0][1]), fmaxf(s1[0][2], s1[0][3]));
      float t1 = fmaxf(fmaxf(s1[1][0], s1[1][1]), fmaxf(s1[1][2], s1[1][3]));
      float t2 = fmaxf(fmaxf(s1[2][0], s1[2][1]), fmaxf(s1[2][2], s1[2][3]));
      float t3 = fmaxf(fmaxf(s1[3][0], s1[3][1]), fmaxf(s1[3][2], s1[3][3]));
      float tmax = fmaxf(fmaxf(t0, t1), fmaxf(t2, t3));
      tmax = fmaxf(tmax, __shfl_xor(tmax, 16));
      tmax = fmaxf(tmax, __shfl_xor(tmax, 32));
      if (!__all(tmax <= m1 + 8.0f)) {
        const float mnew = fmaxf(m1, tmax);
        const float alpha = exp2f(m1 - mnew);
        float a_[4];
#pragma unroll
        for (int j = 0; j < 4; ++j) a_[j] = __shfl(alpha, lhi * 4 + j);
#pragma unroll
        for (int n = 0; n < 4; ++n)
#pragma unroll
          for (int j = 0; j < 4; ++j) o1[n][j] *= a_[j];
        l1 *= alpha;
        m1 = mnew;
      }
      float lloc = 0.f;
#pragma unroll
      for (int kt = 0; kt < 4; ++kt) {
        float p0 = exp2f(s1[kt][0] - m1);
        float p1 = exp2f(s1[kt][1] - m1);
        float p2 = exp2f(s1[kt][2] - m1);
        float p3 = exp2f(s1[kt][3] - m1);
        lloc += (p0 + p1) + (p2 + p3);
        uint2 pk;
        pk.x = cvt_pk_bf16(p0, p1);
        pk.y = cvt_pk_bf16(p2, p3);
        *(uint2*)&P[w][1][l15][kt * 16 + lhi * 4] = pk;
      }
      lloc += __shfl_xor(lloc, 16);
      lloc += __shfl_xor(lloc, 32);
      l1 += lloc;
    }

    asm volatile("s_waitcnt lgkmcnt(0)" ::: "memory");

    // ---- O += P V ; each vf read feeds both subtiles
    __builtin_amdgcn_s_setprio(1);
    bf16x8 pf0[2], pf1[2];
#pragma unroll
    for (int ks = 0; ks < 2; ++ks) {
      pf0[ks] = *(const bf16x8*)&P[w][0][l15][ks * 32 + lhi * 8];
      pf1[ks] = *(const bf16x8*)&P[w][1][l15][ks * 32 + lhi * 8];
    }
    if (do0) {
#pragma unroll
      for (int n = 0; n < 4; ++n) {
        const int vrow = n * 16 + l15;
        const int sw = vrow & 7;
#pragma unroll
        for (int ks = 0; ks < 2; ++ks) {
          bf16x8 vf = *(const bf16x8*)&Vs[cur][vrow * 64 + (((ks * 4 + lhi) ^ sw) * 8)];
          o0[n] = MFMA_BF16(pf0[ks], vf, o0[n]);
          o1[n] = MFMA_BF16(pf1[ks], vf, o1[n]);
        }
      }
    } else {
#pragma unroll
      for (int n = 0; n < 4; ++n) {
        const int vrow = n * 16 + l15;
        const int sw = vrow & 7;
#pragma unroll
        for (int ks = 0; ks < 2; ++ks) {
          bf16x8 vf = *(const bf16x8*)&Vs[cur][vrow * 64 + (((ks * 4 + lhi) ^ sw) * 8)];
          o1[n] = MFMA_BF16(pf1[ks], vf, o1[n]);
        }
      }
    }
    __builtin_amdgcn_s_setprio(0);

    // ---- commit prefetched tile; one barrier per iter
    if (pre) {
      const int nxt = cur ^ 1;
#pragma unroll
      for (int j = 0; j < 2; ++j) {
        const int row = srow + j * 8;
        const int slot = (sd0 ^ (row & 7)) * 8;
        *(uint4*)&Ks[nxt][row * 64 + slot] = kreg[j];
        *(uint4*)&Vs[nxt][row * 64 + slot] = vreg[j];
      }
      cur = nxt;
      __syncthreads();
    }
  }

  // ---- epilogue: normalize by l, store bf16 (both subtiles)
  float linv0[4], linv1[4];
#pragma unroll
  for (int j = 0; j < 4; ++j) {
    linv0[j] = 1.0f / __shfl(l0, lhi * 4 + j);
    linv1[j] = 1.0f / __shfl(l1, lhi * 4 + j);
  }
  const int b_ = bh >> 4, h_ = bh & 15;
#pragma unroll
  for (int j = 0; j < 4; ++j) {
    const int t0_ = qloc0 + lhi * 4 + j;
    const int t1_ = qloc1 + lhi * 4 + j;
    const size_t ro0 = ((size_t)b_ * 2048 + t0_) * 1024 + h_ * 64;
    const size_t ro1 = ((size_t)b_ * 2048 + t1_) * 1024 + h_ * 64;
#pragma unroll
    for (int n = 0; n < 4; ++n) {
      Ab[ro0 + n * 16 + l15] = f2bf(o0[n][j] * linv0[j]);
      Ab[ro1 + n * 16 + l15] = f2bf(o1[n][j] * linv1[j]);
    }
  }
}

// ---------------------------------------------------------------- launch
extern "C" void kernel_launch(void* const* d_in, const int* in_sizes, int n_in,
                              void* d_out, int out_size, void* d_ws, size_t ws_size,
                              hipStream_t stream) {
  const float* x = (const float*)d_in[0];
  const float* Wqkv = (const float*)d_in[1];
  const float* Wout = (const float*)d_in[2];
  float* out = (float*)d_out;

  // workspace layout (bf16 elements), total ~88 MB
  ushort* xb    = (ushort*)d_ws;                     // [8192][1024]
  ushort* wqkvT = xb + (size_t)8192 * 1024;          // [3072][1024]
  ushort* woutT = wqkvT + (size_t)3072 * 1024;       // [1024][1024]
  ushort* qb    = woutT + (size_t)1024 * 1024;       // [64][2048][64]
  ushort* kbuf  = qb + (size_t)64 * 2048 * 64;       // [64][2048][64]
  ushort* vbuf  = kbuf + (size_t)64 * 2048 * 64;     // [64][64][2048] (V^T)
  ushort* ab    = vbuf + (size_t)64 * 2048 * 64;     // [8192][1024]

  convert_f32_bf16<<<8192, 256, 0, stream>>>(x, xb, 8192 * 1024 / 4);
  transpose_w<<<dim3(96, 32), 256, 0, stream>>>(Wqkv, wqkvT, 1024, 3072);
  transpose_w<<<dim3(32, 32), 256, 0, stream>>>(Wout, woutT, 1024, 1024);
  gemm_bf16_kernel<0><<<dim3(64, 24), 256, 0, stream>>>(
      xb, wqkvT, nullptr, qb, kbuf, vbuf, 8192, 3072, 1024);
  attn_kernel<<<1024, 256, 0, stream>>>(qb, kbuf, vbuf, ab);
  gemm_bf16_kernel<1><<<dim3(64, 8), 256, 0, stream>>>(
      ab, woutT, out, nullptr, nullptr, nullptr, 8192, 1024, 1024);
}